// Round 7
// baseline (328.755 us; speedup 1.0000x reference)
//
#include <hip/hip_runtime.h>
#include <stdint.h>

#define NN 50000
#define NE 800000

#define SWZ(j, k) ((j) * 128 + ((k) ^ (((j) & 7) << 2)))

// ---- bf16 helpers (RNE) ----
__device__ inline unsigned short f2bf(float f) {
    union { float f; uint32_t u; } x; x.f = f;
    uint32_t u = x.u;
    return (unsigned short)((u + 0x7fffu + ((u >> 16) & 1u)) >> 16);
}
__device__ inline uint32_t pack2bf(float lo, float hi) {
    return (uint32_t)f2bf(lo) | ((uint32_t)f2bf(hi) << 16);
}
__device__ inline float bf2f(unsigned short h) {
    union { uint32_t u; float f; } c; c.u = ((uint32_t)h) << 16;
    return c.f;
}
__device__ inline float2 bfp2f2(uint32_t v) {
    union { uint32_t u; float f; } a, b;
    a.u = (v & 0xffffu) << 16;
    b.u = v & 0xffff0000u;
    return make_float2(a.f, b.f);
}

#define FMA4(ACC, S, B)                  \
    ACC.x = fmaf(S, B.x, ACC.x);         \
    ACC.y = fmaf(S, B.y, ACC.y);         \
    ACC.z = fmaf(S, B.z, ACC.z);         \
    ACC.w = fmaf(S, B.w, ACC.w);

// ---------- CSR build ----------

__global__ void zero_i(int* p, int n) {
    int i = blockIdx.x * blockDim.x + threadIdx.x;
    if (i < n) p[i] = 0;
}

// histogram + per-edge rank (return value of the atomic IS the rank)
__global__ void hist_rank(const int* __restrict__ dst, int* hist, int* rank, int e) {
    int i = blockIdx.x * blockDim.x + threadIdx.x;
    if (i < e) rank[i] = atomicAdd(hist + dst[i], 1);
}

// per-256-block exclusive scan piece + block sums + dinv (folded)
__global__ void scan1(const int* __restrict__ hist, int* row_ptr, int* bsum,
                      float* dinv, int n) {
    __shared__ int s[256];
    int tid = threadIdx.x;
    int i = blockIdx.x * 256 + tid;
    int v = (i < n) ? hist[i] : 0;
    s[tid] = v;
    __syncthreads();
#pragma unroll
    for (int off = 1; off < 256; off <<= 1) {
        int y = (tid >= off) ? s[tid - off] : 0;
        __syncthreads();
        s[tid] += y;
        __syncthreads();
    }
    if (i < n) {
        row_ptr[i] = s[tid] - v;
        dinv[i] = rsqrtf(1.0f + (float)v);  // +1 self-loop
    }
    if (tid == 255) bsum[blockIdx.x] = s[255];
}

__global__ void scan2(const int* __restrict__ bsum, int* boff, int nb) {
    __shared__ int s[256];
    int tid = threadIdx.x;
    int v = (tid < nb) ? bsum[tid] : 0;
    s[tid] = v;
    __syncthreads();
#pragma unroll
    for (int off = 1; off < 256; off <<= 1) {
        int y = (tid >= off) ? s[tid - off] : 0;
        __syncthreads();
        s[tid] += y;
        __syncthreads();
    }
    if (tid < nb) boff[tid] = s[tid] - v;
}

// atomic-free bucket scatter: position = row_ptr[d] + boff[d>>8] + rank
__global__ void bucket(const int* __restrict__ src, const int* __restrict__ dst,
                       const int* __restrict__ row_ptr, const int* __restrict__ boff,
                       const int* __restrict__ rank, int* __restrict__ csr_src, int e) {
    int i = blockIdx.x * blockDim.x + threadIdx.x;
    if (i < e) {
        int d = dst[i];
        csr_src[row_ptr[d] + boff[d >> 8] + rank[i]] = src[i];
    }
}

// ---------- GEMMs: G written as bf16 ----------

__global__ __launch_bounds__(256) void gemm128(const float* __restrict__ X,
                                               const float* __restrict__ W,
                                               const float* __restrict__ dinv,
                                               unsigned short* __restrict__ G, int n) {
    __shared__ float Ws[128 * 128];  // 64 KB
    int t = threadIdx.x;
    int row0 = blockIdx.x * 128;

    const float4* Wv = (const float4*)W;
    float4* Wsv = (float4*)Ws;
#pragma unroll
    for (int i = 0; i < 16; i++) Wsv[t + i * 256] = Wv[t + i * 256];
    __syncthreads();

    int tx = t & 15;   // col groups: 4tx and 64+4tx
    int ty = t >> 4;   // rows = ty + 16*ri

    const float* xp[8];
#pragma unroll
    for (int ri = 0; ri < 8; ri++) {
        int row = row0 + ty + 16 * ri;
        int rowc = row < n ? row : n - 1;
        xp[ri] = X + (size_t)rowc * 128;
    }

    float4 acc0[8], acc1[8];
#pragma unroll
    for (int ri = 0; ri < 8; ri++) {
        acc0[ri] = make_float4(0.f, 0.f, 0.f, 0.f);
        acc1[ri] = make_float4(0.f, 0.f, 0.f, 0.f);
    }

#pragma unroll 2
    for (int k = 0; k < 128; k += 4) {
        float4 a[8];
#pragma unroll
        for (int ri = 0; ri < 8; ri++) a[ri] = *(const float4*)(xp[ri] + k);
        float4 b0[4], b1[4];
#pragma unroll
        for (int c = 0; c < 4; c++) {
            b0[c] = *(const float4*)(&Ws[(k + c) * 128 + 4 * tx]);
            b1[c] = *(const float4*)(&Ws[(k + c) * 128 + 64 + 4 * tx]);
        }
#pragma unroll
        for (int ri = 0; ri < 8; ri++) {
            FMA4(acc0[ri], a[ri].x, b0[0]);
            FMA4(acc0[ri], a[ri].y, b0[1]);
            FMA4(acc0[ri], a[ri].z, b0[2]);
            FMA4(acc0[ri], a[ri].w, b0[3]);
            FMA4(acc1[ri], a[ri].x, b1[0]);
            FMA4(acc1[ri], a[ri].y, b1[1]);
            FMA4(acc1[ri], a[ri].z, b1[2]);
            FMA4(acc1[ri], a[ri].w, b1[3]);
        }
    }

#pragma unroll
    for (int ri = 0; ri < 8; ri++) {
        int row = row0 + ty + 16 * ri;
        if (row >= n) continue;
        float di = dinv[row];
        uint2 o0, o1;
        o0.x = pack2bf(di * acc0[ri].x, di * acc0[ri].y);
        o0.y = pack2bf(di * acc0[ri].z, di * acc0[ri].w);
        o1.x = pack2bf(di * acc1[ri].x, di * acc1[ri].y);
        o1.y = pack2bf(di * acc1[ri].z, di * acc1[ri].w);
        *(uint2*)(&G[(size_t)row * 128 + 4 * tx]) = o0;
        *(uint2*)(&G[(size_t)row * 128 + 64 + 4 * tx]) = o1;
    }
}

__global__ __launch_bounds__(256) void gemm40(const float* __restrict__ X,
                                              const float* __restrict__ W,
                                              const float* __restrict__ dinv,
                                              unsigned short* __restrict__ G, int n) {
    __shared__ float WsT[40 * 128];
    int t = threadIdx.x;
    int row0 = blockIdx.x * 128;

    const float4* Wv = (const float4*)W;
#pragma unroll
    for (int i = 0; i < 5; i++) {
        int idx = t + i * 256;
        int k = idx / 10;
        int j4 = (idx - k * 10) * 4;
        float4 v = Wv[idx];
        WsT[(j4 + 0) * 128 + (k ^ (((j4 + 0) & 7) << 2))] = v.x;
        WsT[(j4 + 1) * 128 + (k ^ (((j4 + 1) & 7) << 2))] = v.y;
        WsT[(j4 + 2) * 128 + (k ^ (((j4 + 2) & 7) << 2))] = v.z;
        WsT[(j4 + 3) * 128 + (k ^ (((j4 + 3) & 7) << 2))] = v.w;
    }
    __syncthreads();

    int tx = t & 7;
    int ty = t >> 3;

    const float* xp[4];
#pragma unroll
    for (int ri = 0; ri < 4; ri++) {
        int row = row0 + ty + 32 * ri;
        int rowc = row < n ? row : n - 1;
        xp[ri] = X + (size_t)rowc * 128;
    }

    float acc[4][5];
#pragma unroll
    for (int ri = 0; ri < 4; ri++)
#pragma unroll
        for (int ci = 0; ci < 5; ci++) acc[ri][ci] = 0.f;

#pragma unroll 2
    for (int k = 0; k < 128; k += 4) {
        float4 a[4], b[5];
#pragma unroll
        for (int ri = 0; ri < 4; ri++) a[ri] = *(const float4*)(xp[ri] + k);
#pragma unroll
        for (int ci = 0; ci < 5; ci++) b[ci] = *(const float4*)(&WsT[SWZ(tx * 5 + ci, k)]);
#pragma unroll
        for (int ri = 0; ri < 4; ri++)
#pragma unroll
            for (int ci = 0; ci < 5; ci++) {
                acc[ri][ci] = fmaf(a[ri].x, b[ci].x, acc[ri][ci]);
                acc[ri][ci] = fmaf(a[ri].y, b[ci].y, acc[ri][ci]);
                acc[ri][ci] = fmaf(a[ri].z, b[ci].z, acc[ri][ci]);
                acc[ri][ci] = fmaf(a[ri].w, b[ci].w, acc[ri][ci]);
            }
    }

#pragma unroll
    for (int ri = 0; ri < 4; ri++) {
        int row = row0 + ty + 32 * ri;
        if (row >= n) continue;
        float di = dinv[row];
#pragma unroll
        for (int ci = 0; ci < 5; ci++)
            G[(size_t)row * 40 + tx * 5 + ci] = f2bf(di * acc[ri][ci]);
    }
}

// ---------- aggregation: 1 wave/node, uint4 gathers (4 rows/instr) ----------
// lane = (grp<<4)|fl : grp in 0..3 picks the virtual edge of a quad,
// fl in 0..15 picks 16 B (8 bf16 features) within the 256 B row.
// Virtual edge 0 = self-loop; edges j>0 come from csr_src[p+j-1].
__global__ __launch_bounds__(256) void aggregate128(const unsigned short* __restrict__ G,
                                                    const int* __restrict__ row_ptr,
                                                    const int* __restrict__ boff,
                                                    const int* __restrict__ hist,
                                                    const int* __restrict__ csr_src,
                                                    const float* __restrict__ dinv,
                                                    const float* __restrict__ b,
                                                    float* __restrict__ Y, int n) {
    int node = blockIdx.x * 4 + (threadIdx.x >> 6);
    if (node >= n) return;
    int lane = threadIdx.x & 63;
    int grp = lane >> 4;
    int fl = lane & 15;
    const uint4* Gq = (const uint4*)G;  // 16 uint4 per row

    float2 a0 = make_float2(0.f, 0.f), a1 = a0, a2 = a0, a3 = a0;
    int p = row_ptr[node] + boff[node >> 8];
    int cnt = hist[node] + 1;  // + self-loop

    for (int j = 0; j < cnt; j += 8) {
        int e0 = j + grp, e1 = e0 + 4;
        bool v0 = e0 < cnt, v1 = e1 < cnt;
        int i0 = 0, i1 = 0;
        if (v0) i0 = (e0 == 0) ? node : csr_src[p + e0 - 1];
        if (v1) i1 = csr_src[p + e1 - 1];  // e1 >= 4 > 0
        uint4 u0, u1;
        if (v0) u0 = Gq[(size_t)i0 * 16 + fl];
        if (v1) u1 = Gq[(size_t)i1 * 16 + fl];
        if (v0) {
            float2 f;
            f = bfp2f2(u0.x); a0.x += f.x; a0.y += f.y;
            f = bfp2f2(u0.y); a1.x += f.x; a1.y += f.y;
            f = bfp2f2(u0.z); a2.x += f.x; a2.y += f.y;
            f = bfp2f2(u0.w); a3.x += f.x; a3.y += f.y;
        }
        if (v1) {
            float2 f;
            f = bfp2f2(u1.x); a0.x += f.x; a0.y += f.y;
            f = bfp2f2(u1.y); a1.x += f.x; a1.y += f.y;
            f = bfp2f2(u1.z); a2.x += f.x; a2.y += f.y;
            f = bfp2f2(u1.w); a3.x += f.x; a3.y += f.y;
        }
    }

    // reduce across the 4 groups (lane bits 4,5); all lanes end with the sum
#pragma unroll
    for (int m = 16; m <= 32; m <<= 1) {
        a0.x += __shfl_xor(a0.x, m, 64); a0.y += __shfl_xor(a0.y, m, 64);
        a1.x += __shfl_xor(a1.x, m, 64); a1.y += __shfl_xor(a1.y, m, 64);
        a2.x += __shfl_xor(a2.x, m, 64); a2.y += __shfl_xor(a2.y, m, 64);
        a3.x += __shfl_xor(a3.x, m, 64); a3.y += __shfl_xor(a3.y, m, 64);
    }

    // lane (grp,fl) writes features fl*8 + grp*2 .. +1
    float2 w = grp < 2 ? (grp == 0 ? a0 : a1) : (grp == 2 ? a2 : a3);
    int f0 = fl * 8 + grp * 2;
    float di = dinv[node];
    float2 bb = *(const float2*)(b + f0);
    float vx = fmaf(di, w.x, bb.x);
    float vy = fmaf(di, w.y, bb.y);
    float2 o = make_float2(vx > 0.f ? vx : 0.f, vy > 0.f ? vy : 0.f);
    *(float2*)(Y + (size_t)node * 128 + f0) = o;
}

__global__ __launch_bounds__(256) void aggregate40_lsm(const unsigned short* __restrict__ G,
                                                       const int* __restrict__ row_ptr,
                                                       const int* __restrict__ boff,
                                                       const int* __restrict__ hist,
                                                       const int* __restrict__ csr_src,
                                                       const float* __restrict__ dinv,
                                                       const float* __restrict__ b,
                                                       float* __restrict__ Y, int n) {
    int node = blockIdx.x * 4 + (threadIdx.x >> 6);
    if (node >= n) return;
    int lane = threadIdx.x & 63;
    bool act = lane < 40;
    int lc = act ? lane : 0;
    float acc = act ? bf2f(G[(size_t)node * 40 + lane]) : 0.f;
    int p = row_ptr[node] + boff[node >> 8];
    int p1 = p + hist[node];
    for (; p + 3 < p1; p += 4) {
        int s0 = csr_src[p], s1 = csr_src[p + 1], s2 = csr_src[p + 2], s3 = csr_src[p + 3];
        float f0 = bf2f(G[(size_t)s0 * 40 + lc]);
        float f1 = bf2f(G[(size_t)s1 * 40 + lc]);
        float f2 = bf2f(G[(size_t)s2 * 40 + lc]);
        float f3 = bf2f(G[(size_t)s3 * 40 + lc]);
        acc += (f0 + f1) + (f2 + f3);
    }
    for (; p < p1; ++p) acc += bf2f(G[(size_t)csr_src[p] * 40 + lc]);

    float v = act ? fmaf(dinv[node], acc, b[lane]) : -1e30f;
    float m = v;
#pragma unroll
    for (int off = 32; off > 0; off >>= 1) m = fmaxf(m, __shfl_xor(m, off, 64));
    float ex = act ? expf(v - m) : 0.f;
    float s_ = ex;
#pragma unroll
    for (int off = 32; off > 0; off >>= 1) s_ += __shfl_xor(s_, off, 64);
    float ls = logf(s_);
    if (act) Y[(size_t)node * 40 + lane] = v - m - ls;
}

// ---------- launch ----------

extern "C" void kernel_launch(void* const* d_in, const int* in_sizes, int n_in,
                              void* d_out, int out_size, void* d_ws, size_t ws_size,
                              hipStream_t stream) {
    const float* x  = (const float*)d_in[0];
    const int*   ei = (const int*)d_in[1];
    const float* W1 = (const float*)d_in[2];
    const float* b1 = (const float*)d_in[3];
    const float* W2 = (const float*)d_in[4];
    const float* b2 = (const float*)d_in[5];
    const float* W3 = (const float*)d_in[6];
    const float* b3 = (const float*)d_in[7];
    float* out = (float*)d_out;

    const int n = NN, e = NE;
    const int* srcI = ei;
    const int* dstI = ei + e;

    char* ws = (char*)d_ws;
    int*   hist    = (int*)ws;                               // n
    float* dinv    = (float*)(ws + 200704);                  // n
    int*   row_ptr = (int*)(ws + 401408);                    // n
    int*   bsum    = (int*)(ws + 602112);                    // 256
    int*   boff    = (int*)(ws + 603136);                    // 256
    int*   rank    = (int*)(ws + 604160);                    // E
    int*   csr_src = (int*)(ws + 3804160);                   // E
    unsigned short* bufG = (unsigned short*)(ws + 7004160);  // n*128 bf16
    float* bufA    = (float*)(ws + 7004160 + 12800000);      // n*128 fp32

    int nb = (n + 255) / 256;

    zero_i<<<nb, 256, 0, stream>>>(hist, n);
    hist_rank<<<(e + 255) / 256, 256, 0, stream>>>(dstI, hist, rank, e);
    scan1<<<nb, 256, 0, stream>>>(hist, row_ptr, bsum, dinv, n);
    scan2<<<1, 256, 0, stream>>>(bsum, boff, nb);
    bucket<<<(e + 255) / 256, 256, 0, stream>>>(srcI, dstI, row_ptr, boff, rank, csr_src, e);

    unsigned gg = (unsigned)((n + 127) / 128);
    unsigned ga = (unsigned)((n + 3) / 4);

    // layer 1
    gemm128<<<gg, 256, 0, stream>>>(x, W1, dinv, bufG, n);
    aggregate128<<<ga, 256, 0, stream>>>(bufG, row_ptr, boff, hist, csr_src, dinv, b1, bufA, n);
    // layer 2
    gemm128<<<gg, 256, 0, stream>>>(bufA, W2, dinv, bufG, n);
    aggregate128<<<ga, 256, 0, stream>>>(bufG, row_ptr, boff, hist, csr_src, dinv, b2, bufA, n);
    // layer 3
    gemm40<<<gg, 256, 0, stream>>>(bufA, W3, dinv, bufG, n);
    aggregate40_lsm<<<ga, 256, 0, stream>>>(bufG, row_ptr, boff, hist, csr_src, dinv, b3, out, n);
}

// Round 8
// 312.201 us; speedup vs baseline: 1.0530x; 1.0530x over previous
//
#include <hip/hip_runtime.h>
#include <stdint.h>

#define NN 50000
#define NE 800000

typedef __attribute__((ext_vector_type(8))) short bfx8;   // 8 bf16 (4 VGPRs)
typedef __attribute__((ext_vector_type(4))) float f32x4;  // MFMA acc

// ---- bf16 helpers (RNE) ----
__device__ inline unsigned short f2bf(float f) {
    union { float f; uint32_t u; } x; x.f = f;
    uint32_t u = x.u;
    return (unsigned short)((u + 0x7fffu + ((u >> 16) & 1u)) >> 16);
}
__device__ inline uint32_t pack2bf(float lo, float hi) {
    return (uint32_t)f2bf(lo) | ((uint32_t)f2bf(hi) << 16);
}
__device__ inline float bf2f(unsigned short h) {
    union { uint32_t u; float f; } c; c.u = ((uint32_t)h) << 16;
    return c.f;
}
__device__ inline float2 bfp2f2(uint32_t v) {
    union { uint32_t u; float f; } a, b;
    a.u = (v & 0xffffu) << 16;
    b.u = v & 0xffff0000u;
    return make_float2(a.f, b.f);
}
__device__ inline bfx8 ld8(const unsigned short* p) {
    union { uint4 u; bfx8 v; } c;
    c.u = *(const uint4*)p;
    return c.v;
}

// ---------- CSR build ----------

__global__ void zero_i(int* p, int n) {
    int i = blockIdx.x * blockDim.x + threadIdx.x;
    if (i < n) p[i] = 0;
}

__global__ void hist_rank(const int* __restrict__ dst, int* hist,
                          unsigned short* rank, int e) {
    int i = blockIdx.x * blockDim.x + threadIdx.x;
    if (i < e) rank[i] = (unsigned short)atomicAdd(hist + dst[i], 1);
}

__global__ void scan1(const int* __restrict__ hist, int* row_ptr, int* bsum,
                      float* dinv, int n) {
    __shared__ int s[256];
    int tid = threadIdx.x;
    int i = blockIdx.x * 256 + tid;
    int v = (i < n) ? hist[i] : 0;
    s[tid] = v;
    __syncthreads();
#pragma unroll
    for (int off = 1; off < 256; off <<= 1) {
        int y = (tid >= off) ? s[tid - off] : 0;
        __syncthreads();
        s[tid] += y;
        __syncthreads();
    }
    if (i < n) {
        row_ptr[i] = s[tid] - v;
        dinv[i] = rsqrtf(1.0f + (float)v);
    }
    if (tid == 255) bsum[blockIdx.x] = s[255];
}

__global__ void scan2(const int* __restrict__ bsum, int* boff, int nb) {
    __shared__ int s[256];
    int tid = threadIdx.x;
    int v = (tid < nb) ? bsum[tid] : 0;
    s[tid] = v;
    __syncthreads();
#pragma unroll
    for (int off = 1; off < 256; off <<= 1) {
        int y = (tid >= off) ? s[tid - off] : 0;
        __syncthreads();
        s[tid] += y;
        __syncthreads();
    }
    if (tid < nb) boff[tid] = s[tid] - v;
}

__global__ void bucket(const int* __restrict__ src, const int* __restrict__ dst,
                       const int* __restrict__ row_ptr, const int* __restrict__ boff,
                       const unsigned short* __restrict__ rank,
                       unsigned short* __restrict__ csr_src, int e) {
    int i = blockIdx.x * blockDim.x + threadIdx.x;
    if (i < e) {
        int d = dst[i];
        csr_src[row_ptr[d] + boff[d >> 8] + (int)rank[i]] = (unsigned short)src[i];
    }
}

// ---------- prep: x -> bf16, W1/W2/W3 -> bf16 transposed WT[n][k] ----------
__global__ void prep(const float* __restrict__ x,
                     const float* __restrict__ W1, const float* __restrict__ W2,
                     const float* __restrict__ W3,
                     unsigned short* __restrict__ bufX,
                     unsigned short* __restrict__ WT1, unsigned short* __restrict__ WT2,
                     unsigned short* __restrict__ WT3) {
    int bid = blockIdx.x;
    if (bid < 6250) {                       // x convert: 1,600,000 float4s exactly
        int i = bid * 256 + threadIdx.x;
        float4 v = ((const float4*)x)[i];
        uint2 o;
        o.x = pack2bf(v.x, v.y);
        o.y = pack2bf(v.z, v.w);
        ((uint2*)bufX)[i] = o;
    } else {                                // transposes: 38912 elements exactly
        int w = (bid - 6250) * 256 + threadIdx.x;
        if (w < 16384) {
            int nn = w >> 7, k = w & 127;
            WT1[nn * 128 + k] = f2bf(W1[k * 128 + nn]);
        } else if (w < 32768) {
            int w2 = w - 16384, nn = w2 >> 7, k = w2 & 127;
            WT2[nn * 128 + k] = f2bf(W2[k * 128 + nn]);
        } else {
            int w2 = w - 32768, nn = w2 >> 7, k = w2 & 127;  // 48 x 128, zero-pad
            WT3[nn * 128 + k] = (nn < 40) ? f2bf(W3[k * 40 + nn]) : (unsigned short)0;
        }
    }
}

// ---------- MFMA GEMM: G[r][c] = dinv[r] * sum_k A[r][k] WT[c][k] ----------
// 4 waves/block, each wave: 16 rows x 128 cols (8 col-tiles of 16x16x32 MFMA).
// A-frag: lane holds A[row=lane&15][k=quad*8+j]; B-frag: WT[col=lane&15][k=quad*8+j];
// D: row=quad*4+reg, col=lane&15 (verified mapping). No LDS: WT is 32 KB, L1/L2-hot.
__global__ __launch_bounds__(256) void gemm128_mfma(const unsigned short* __restrict__ A,
                                                    const unsigned short* __restrict__ WT,
                                                    const float* __restrict__ dinv,
                                                    unsigned short* __restrict__ G, int n) {
    int wave = threadIdx.x >> 6;
    int lane = threadIdx.x & 63;
    int quad = lane >> 4;
    int c = lane & 15;
    int rowbase = blockIdx.x * 64 + wave * 16;

    int arow = rowbase + c;
    if (arow >= n) arow = n - 1;
    const unsigned short* ap = A + (size_t)arow * 128 + quad * 8;
    bfx8 a[4];
#pragma unroll
    for (int kc = 0; kc < 4; kc++) a[kc] = ld8(ap + kc * 32);

    f32x4 acc[8];
#pragma unroll
    for (int ct = 0; ct < 8; ct++) acc[ct] = (f32x4){0.f, 0.f, 0.f, 0.f};

#pragma unroll
    for (int ct = 0; ct < 8; ct++) {
        const unsigned short* bp = WT + (size_t)(ct * 16 + c) * 128 + quad * 8;
#pragma unroll
        for (int kc = 0; kc < 4; kc++) {
            bfx8 b = ld8(bp + kc * 32);
            acc[ct] = __builtin_amdgcn_mfma_f32_16x16x32_bf16(a[kc], b, acc[ct], 0, 0, 0);
        }
    }

    int r0 = rowbase + quad * 4;
    float di[4];
#pragma unroll
    for (int r = 0; r < 4; r++) {
        int rr = r0 + r;
        di[r] = dinv[rr < n ? rr : 0];
    }
    bool odd = lane & 1;
#pragma unroll
    for (int ct = 0; ct < 8; ct++) {
        float x0 = acc[ct][0], x1 = acc[ct][1], x2 = acc[ct][2], x3 = acc[ct][3];
        float y0 = __shfl_xor(x0, 1, 64), y1 = __shfl_xor(x1, 1, 64);
        float y2 = __shfl_xor(x2, 1, 64), y3 = __shfl_xor(x3, 1, 64);
        int colp = ct * 16 + (c & ~1);
        if (!odd) {
            if (r0 + 0 < n) *(uint32_t*)(&G[(size_t)(r0 + 0) * 128 + colp]) = pack2bf(di[0] * x0, di[0] * y0);
            if (r0 + 1 < n) *(uint32_t*)(&G[(size_t)(r0 + 1) * 128 + colp]) = pack2bf(di[1] * x1, di[1] * y1);
        } else {
            if (r0 + 2 < n) *(uint32_t*)(&G[(size_t)(r0 + 2) * 128 + colp]) = pack2bf(di[2] * y2, di[2] * x2);
            if (r0 + 3 < n) *(uint32_t*)(&G[(size_t)(r0 + 3) * 128 + colp]) = pack2bf(di[3] * y3, di[3] * x3);
        }
    }
}

// K=40 (48-padded WT3): 3 col-tiles, store guard colp<40; G row stride 40.
__global__ __launch_bounds__(256) void gemm40_mfma(const unsigned short* __restrict__ A,
                                                   const unsigned short* __restrict__ WT,
                                                   const float* __restrict__ dinv,
                                                   unsigned short* __restrict__ G, int n) {
    int wave = threadIdx.x >> 6;
    int lane = threadIdx.x & 63;
    int quad = lane >> 4;
    int c = lane & 15;
    int rowbase = blockIdx.x * 64 + wave * 16;

    int arow = rowbase + c;
    if (arow >= n) arow = n - 1;
    const unsigned short* ap = A + (size_t)arow * 128 + quad * 8;
    bfx8 a[4];
#pragma unroll
    for (int kc = 0; kc < 4; kc++) a[kc] = ld8(ap + kc * 32);

    f32x4 acc[3];
#pragma unroll
    for (int ct = 0; ct < 3; ct++) acc[ct] = (f32x4){0.f, 0.f, 0.f, 0.f};

#pragma unroll
    for (int ct = 0; ct < 3; ct++) {
        const unsigned short* bp = WT + (size_t)(ct * 16 + c) * 128 + quad * 8;
#pragma unroll
        for (int kc = 0; kc < 4; kc++) {
            bfx8 b = ld8(bp + kc * 32);
            acc[ct] = __builtin_amdgcn_mfma_f32_16x16x32_bf16(a[kc], b, acc[ct], 0, 0, 0);
        }
    }

    int r0 = rowbase + quad * 4;
    float di[4];
#pragma unroll
    for (int r = 0; r < 4; r++) {
        int rr = r0 + r;
        di[r] = dinv[rr < n ? rr : 0];
    }
    bool odd = lane & 1;
#pragma unroll
    for (int ct = 0; ct < 3; ct++) {
        float x0 = acc[ct][0], x1 = acc[ct][1], x2 = acc[ct][2], x3 = acc[ct][3];
        float y0 = __shfl_xor(x0, 1, 64), y1 = __shfl_xor(x1, 1, 64);
        float y2 = __shfl_xor(x2, 1, 64), y3 = __shfl_xor(x3, 1, 64);
        int colp = ct * 16 + (c & ~1);
        if (colp >= 40) continue;
        if (!odd) {
            if (r0 + 0 < n) *(uint32_t*)(&G[(size_t)(r0 + 0) * 40 + colp]) = pack2bf(di[0] * x0, di[0] * y0);
            if (r0 + 1 < n) *(uint32_t*)(&G[(size_t)(r0 + 1) * 40 + colp]) = pack2bf(di[1] * x1, di[1] * y1);
        } else {
            if (r0 + 2 < n) *(uint32_t*)(&G[(size_t)(r0 + 2) * 40 + colp]) = pack2bf(di[2] * y2, di[2] * x2);
            if (r0 + 3 < n) *(uint32_t*)(&G[(size_t)(r0 + 3) * 40 + colp]) = pack2bf(di[3] * y3, di[3] * x3);
        }
    }
}

// ---------- aggregation: 1 wave/node, 2 bf16 features/lane, bf16 out ----------

__global__ __launch_bounds__(256) void aggregate128(const unsigned short* __restrict__ G,
                                                    const int* __restrict__ row_ptr,
                                                    const int* __restrict__ boff,
                                                    const int* __restrict__ hist,
                                                    const unsigned short* __restrict__ csr_src,
                                                    const float* __restrict__ dinv,
                                                    const float* __restrict__ b,
                                                    unsigned short* __restrict__ Y, int n) {
    int node = blockIdx.x * 4 + (threadIdx.x >> 6);
    if (node >= n) return;
    int l = threadIdx.x & 63;
    const uint32_t* Gr = (const uint32_t*)G;

    float2 acc = bfp2f2(Gr[(size_t)node * 64 + l]);  // self-loop
    int p = row_ptr[node] + boff[node >> 8];
    int p1 = p + hist[node];
    for (; p + 7 < p1; p += 8) {
        int s0 = csr_src[p],     s1 = csr_src[p + 1], s2 = csr_src[p + 2], s3 = csr_src[p + 3];
        int s4 = csr_src[p + 4], s5 = csr_src[p + 5], s6 = csr_src[p + 6], s7 = csr_src[p + 7];
        float2 f0 = bfp2f2(Gr[(size_t)s0 * 64 + l]), f1 = bfp2f2(Gr[(size_t)s1 * 64 + l]);
        float2 f2 = bfp2f2(Gr[(size_t)s2 * 64 + l]), f3 = bfp2f2(Gr[(size_t)s3 * 64 + l]);
        float2 f4 = bfp2f2(Gr[(size_t)s4 * 64 + l]), f5 = bfp2f2(Gr[(size_t)s5 * 64 + l]);
        float2 f6 = bfp2f2(Gr[(size_t)s6 * 64 + l]), f7 = bfp2f2(Gr[(size_t)s7 * 64 + l]);
        acc.x += ((f0.x + f1.x) + (f2.x + f3.x)) + ((f4.x + f5.x) + (f6.x + f7.x));
        acc.y += ((f0.y + f1.y) + (f2.y + f3.y)) + ((f4.y + f5.y) + (f6.y + f7.y));
    }
    for (; p < p1; ++p) {
        float2 f = bfp2f2(Gr[(size_t)csr_src[p] * 64 + l]);
        acc.x += f.x; acc.y += f.y;
    }
    float di = dinv[node];
    float vx = fmaf(di, acc.x, b[2 * l]);
    float vy = fmaf(di, acc.y, b[2 * l + 1]);
    ((uint32_t*)Y)[(size_t)node * 64 + l] = pack2bf(vx > 0.f ? vx : 0.f, vy > 0.f ? vy : 0.f);
}

__global__ __launch_bounds__(256) void aggregate40_lsm(const unsigned short* __restrict__ G,
                                                       const int* __restrict__ row_ptr,
                                                       const int* __restrict__ boff,
                                                       const int* __restrict__ hist,
                                                       const unsigned short* __restrict__ csr_src,
                                                       const float* __restrict__ dinv,
                                                       const float* __restrict__ b,
                                                       float* __restrict__ Y, int n) {
    int node = blockIdx.x * 4 + (threadIdx.x >> 6);
    if (node >= n) return;
    int lane = threadIdx.x & 63;
    bool act = lane < 40;
    int lc = act ? lane : 0;
    float acc = act ? bf2f(G[(size_t)node * 40 + lane]) : 0.f;
    int p = row_ptr[node] + boff[node >> 8];
    int p1 = p + hist[node];
    for (; p + 3 < p1; p += 4) {
        int s0 = csr_src[p], s1 = csr_src[p + 1], s2 = csr_src[p + 2], s3 = csr_src[p + 3];
        float f0 = bf2f(G[(size_t)s0 * 40 + lc]);
        float f1 = bf2f(G[(size_t)s1 * 40 + lc]);
        float f2 = bf2f(G[(size_t)s2 * 40 + lc]);
        float f3 = bf2f(G[(size_t)s3 * 40 + lc]);
        acc += (f0 + f1) + (f2 + f3);
    }
    for (; p < p1; ++p) acc += bf2f(G[(size_t)csr_src[p] * 40 + lc]);

    float v = act ? fmaf(dinv[node], acc, b[lane]) : -1e30f;
    float m = v;
#pragma unroll
    for (int off = 32; off > 0; off >>= 1) m = fmaxf(m, __shfl_xor(m, off, 64));
    float ex = act ? expf(v - m) : 0.f;
    float s_ = ex;
#pragma unroll
    for (int off = 32; off > 0; off >>= 1) s_ += __shfl_xor(s_, off, 64);
    float ls = logf(s_);
    if (act) Y[(size_t)node * 40 + lane] = v - m - ls;
}

// ---------- launch ----------

extern "C" void kernel_launch(void* const* d_in, const int* in_sizes, int n_in,
                              void* d_out, int out_size, void* d_ws, size_t ws_size,
                              hipStream_t stream) {
    const float* x  = (const float*)d_in[0];
    const int*   ei = (const int*)d_in[1];
    const float* W1 = (const float*)d_in[2];
    const float* b1 = (const float*)d_in[3];
    const float* W2 = (const float*)d_in[4];
    const float* b2 = (const float*)d_in[5];
    const float* W3 = (const float*)d_in[6];
    const float* b3 = (const float*)d_in[7];
    float* out = (float*)d_out;

    const int n = NN, e = NE;
    const int* srcI = ei;
    const int* dstI = ei + e;

    char* ws = (char*)d_ws;
    int*   hist    = (int*)ws;                                   // n ints
    float* dinv    = (float*)(ws + 200704);
    int*   row_ptr = (int*)(ws + 401408);
    int*   bsum    = (int*)(ws + 602112);
    int*   boff    = (int*)(ws + 603136);
    unsigned short* rank    = (unsigned short*)(ws + 604160);    // E ushort
    unsigned short* csr_src = (unsigned short*)(ws + 2204160);   // E ushort
    unsigned short* WT1     = (unsigned short*)(ws + 3804160);   // 128x128 bf16
    unsigned short* WT2     = (unsigned short*)(ws + 3836928);
    unsigned short* WT3     = (unsigned short*)(ws + 3869696);   // 48x128 bf16
    unsigned short* bufX    = (unsigned short*)(ws + 3881984);   // n*128 bf16
    unsigned short* bufG    = (unsigned short*)(ws + 16681984);  // n*128 bf16
    unsigned short* bufA    = (unsigned short*)(ws + 29481984);  // n*128 bf16
    unsigned short* G40     = bufX;                              // reuse after layer 1

    int nb = (n + 255) / 256;

    prep<<<6250 + 152, 256, 0, stream>>>(x, W1, W2, W3, bufX, WT1, WT2, WT3);
    zero_i<<<nb, 256, 0, stream>>>(hist, n);
    hist_rank<<<(e + 255) / 256, 256, 0, stream>>>(dstI, hist, rank, e);
    scan1<<<nb, 256, 0, stream>>>(hist, row_ptr, bsum, dinv, n);
    scan2<<<1, 256, 0, stream>>>(bsum, boff, nb);
    bucket<<<(e + 255) / 256, 256, 0, stream>>>(srcI, dstI, row_ptr, boff, rank, csr_src, e);

    unsigned gg = (unsigned)((n + 63) / 64);  // 782
    unsigned ga = (unsigned)((n + 3) / 4);

    // layer 1
    gemm128_mfma<<<gg, 256, 0, stream>>>(bufX, WT1, dinv, bufG, n);
    aggregate128<<<ga, 256, 0, stream>>>(bufG, row_ptr, boff, hist, csr_src, dinv, b1, bufA, n);
    // layer 2
    gemm128_mfma<<<gg, 256, 0, stream>>>(bufA, WT2, dinv, bufG, n);
    aggregate128<<<ga, 256, 0, stream>>>(bufG, row_ptr, boff, hist, csr_src, dinv, b2, bufA, n);
    // layer 3
    gemm40_mfma<<<gg, 256, 0, stream>>>(bufA, WT3, dinv, G40, n);
    aggregate40_lsm<<<ga, 256, 0, stream>>>(G40, row_ptr, boff, hist, csr_src, dinv, b3, out, n);
}